// Round 17
// baseline (255.774 us; speedup 1.0000x reference)
//
#include <hip/hip_runtime.h>
#include <math.h>

#define N_NODES 50000
#define N_EDGES 800000
#define NBK 196          // dst buckets of 256 nodes: bucket = dst >> 8
#define BCAP 6144        // max edges per bucket handled in LDS (mean 4082, sigma 64)

typedef short short8 __attribute__((ext_vector_type(8)));
typedef float f32x4 __attribute__((ext_vector_type(4)));
typedef float f32x2 __attribute__((ext_vector_type(2)));

// ---------------- bf16 / fp8 helpers ----------------
__device__ inline unsigned short f2bf(float v) {
  unsigned u = __float_as_uint(v);
  u += 0x7FFFu + ((u >> 16) & 1u);  // round-to-nearest-even
  return (unsigned short)(u >> 16);
}
__device__ inline float bf2f(unsigned short b) {
  return __uint_as_float(((unsigned)b) << 16);
}
__device__ inline float bflo(unsigned u) { return __uint_as_float(u << 16); }
__device__ inline float bfhi(unsigned u) { return __uint_as_float(u & 0xFFFF0000u); }
// fp8 e4m3 (OCP on gfx950); decode selector must be an immediate -> template param.
__device__ inline unsigned char f2fp8(float v) {
  return (unsigned char)(__builtin_amdgcn_cvt_pk_fp8_f32(v, 0.f, 0, false) & 0xFF);
}
template <bool HI>
__device__ inline f32x2 fp8dec(unsigned u) {
  return __builtin_amdgcn_cvt_pk_f32_fp8(u, HI);
}

#define SCL 0.17677669529663687f   // 1/sqrt(32), folded into Wq/bq at prep

// ---------------- fused prep: weight concat/transpose + bucket histogram ----------------
#define W1_B 256      // 512*128 / 256
#define W2_B 64       // 128*128 / 256
__global__ void prep_fused(const float* __restrict__ Wq1, const float* __restrict__ Wk1,
                           const float* __restrict__ Wv1, const float* __restrict__ Ws1,
                           const float* __restrict__ bq1, const float* __restrict__ bk1,
                           const float* __restrict__ bv1, const float* __restrict__ bs1,
                           const float* __restrict__ Wq2, const float* __restrict__ Wk2,
                           const float* __restrict__ Wv2, const float* __restrict__ Ws2,
                           const float* __restrict__ bq2, const float* __restrict__ bk2,
                           const float* __restrict__ bv2, const float* __restrict__ bs2,
                           unsigned short* __restrict__ Wt1, float* __restrict__ bcat1,
                           unsigned short* __restrict__ Wt2, float* __restrict__ bcat2,
                           const int* __restrict__ ei, int* __restrict__ bhist, int E) {
  const int b = blockIdx.x, tid = threadIdx.x;
  if (b < W1_B) {
    int i = b * 256 + tid;   // over 512*128
    int c = i >> 7, k = i & 127;
    int mi = c >> 7, lc = c & 127;
    const float* W = (mi == 0) ? Wq1 : (mi == 1) ? Wk1 : (mi == 2) ? Wv1 : Ws1;
    float scl = (mi == 0) ? SCL : 1.f;
    Wt1[i] = f2bf(W[(size_t)k * 128 + lc] * scl);
    if (i < 512) {
      int bm = i >> 7, bl = i & 127;
      const float* bb = (bm == 0) ? bq1 : (bm == 1) ? bk1 : (bm == 2) ? bv1 : bs1;
      bcat1[i] = bb[bl] * ((bm == 0) ? SCL : 1.f);
    }
  } else if (b < W1_B + W2_B) {
    int i = (b - W1_B) * 256 + tid;  // over 128*128
    int c = i >> 7, k = i & 127;
    int mi = c >> 5, lc = c & 31;
    const float* W = (mi == 0) ? Wq2 : (mi == 1) ? Wk2 : (mi == 2) ? Wv2 : Ws2;
    float scl = (mi == 0) ? SCL : 1.f;
    Wt2[i] = f2bf(W[(size_t)k * 32 + lc] * scl);
    if (i < 128) {
      int bm = i >> 5, bl = i & 31;
      const float* bb = (bm == 0) ? bq2 : (bm == 1) ? bk2 : (bm == 2) ? bv2 : bs2;
      bcat2[i] = bb[bl] * ((bm == 0) ? SCL : 1.f);
    }
  } else {
    __shared__ int h[NBK];
    for (int i = tid; i < NBK; i += 256) h[i] = 0;
    __syncthreads();
    int e = (b - W1_B - W2_B) * 4096 + tid;
#pragma unroll
    for (int p = 0; p < 16; ++p, e += 256)
      if (e < E) atomicAdd(&h[ei[E + e] >> 8], 1);
    __syncthreads();
    for (int i = tid; i < NBK; i += 256)
      if (h[i]) atomicAdd(&bhist[i], h[i]);
  }
}

// ================= bucket scan =================
__global__ void bucket_scan(const int* __restrict__ bhist, int* __restrict__ boff,
                            int* __restrict__ bcur) {
  __shared__ int s[256];
  int t = threadIdx.x;
  int v = (t < NBK) ? bhist[t] : 0;
  s[t] = v;
  __syncthreads();
#pragma unroll
  for (int off = 1; off < 256; off <<= 1) {
    int u = (t >= off) ? s[t - off] : 0;
    __syncthreads();
    s[t] += u;
    __syncthreads();
  }
  if (t < NBK) {
    int excl = s[t] - v;
    boff[t] = excl;
    bcur[t] = excl;
  }
  if (t == NBK - 1) boff[NBK] = s[t];
}

// ================= FUSED: bucket_scatter (blocks [0,EBS), 2048 edges each) =================
// ================= + conv1 GEMM (blocks [EBS, EBS+GB), 64 rows x 512 cols) =================
// GEMM: A staged from fp32 x (bf16 in-flight); wave0->Q(bf16), wave1->K(fp8),
// wave2->V(fp8), wave3->SK(bf16). KV fp8 row (256 B/node) INTERLEAVED:
// byte 4t+{0,1} = K[2t,2t+1], byte 4t+{2,3} = V[2t,2t+1].
// ebuck packed: (src<<8) | (dst & 255).
__global__ __launch_bounds__(256) void scatter_gemm1(
    const int* __restrict__ ei, int* __restrict__ bcur, int* __restrict__ ebuck, int E, int EBS,
    const float* __restrict__ X, const unsigned short* __restrict__ Wt,
    const float* __restrict__ bcat, unsigned short* __restrict__ Q1b,
    unsigned short* __restrict__ SK1, unsigned char* __restrict__ KV8, int M) {
  __shared__ __align__(16) unsigned char L[3][64 * 272];  // 52.2 KB
  const int tid = threadIdx.x;

  if ((int)blockIdx.x < EBS) {
    // ---------- scatter path: 2048 edges, 8 per thread ----------
    int* lh = (int*)L[0];
    for (int i = tid; i < NBK; i += 256) lh[i] = 0;
    __syncthreads();
    const int e0 = blockIdx.x * 2048;
    int pks[8], bks[8];
#pragma unroll
    for (int p = 0; p < 8; ++p) {
      int e = e0 + p * 256 + tid;
      if (e < E) {
        int src = ei[e], dst = ei[E + e];
        pks[p] = (src << 8) | (dst & 255);
        bks[p] = dst >> 8;
        atomicAdd(&lh[bks[p]], 1);
      } else bks[p] = -1;
    }
    __syncthreads();
    for (int i = tid; i < NBK; i += 256)
      if (lh[i]) lh[i] = atomicAdd(&bcur[i], lh[i]);
    __syncthreads();
#pragma unroll
    for (int p = 0; p < 8; ++p) {
      if (bks[p] >= 0) {
        int slot = atomicAdd(&lh[bks[p]], 1);
        ebuck[slot] = pks[p];
      }
    }
    return;
  }

  // ---------- GEMM path ----------
  unsigned short* As = (unsigned short*)L[0];             // stride 136 shorts
  const int bm = (blockIdx.x - EBS) * 64;
  const int wave = tid >> 6, lane = tid & 63;
  const int lr = lane & 15, q = lane >> 4;

#pragma unroll
  for (int p = 0; p < 8; ++p) {
    int f = tid + p * 256;          // 0..2047 float4s
    int row = f >> 5, c4 = f & 31;
    int gm = bm + row; if (gm >= M) gm = 0;
    float4 v = *(const float4*)(X + (size_t)gm * 128 + c4 * 4);
    ushort4 o;
    o.x = f2bf(v.x); o.y = f2bf(v.y); o.z = f2bf(v.z); o.w = f2bf(v.w);
    *(ushort4*)&As[row * 136 + c4 * 4] = o;
  }
  __syncthreads();

  const int colbase = wave * 128;
  f32x4 acc[4][8];
#pragma unroll
  for (int i = 0; i < 4; ++i)
#pragma unroll
    for (int j = 0; j < 8; ++j) acc[i][j] = (f32x4){0.f, 0.f, 0.f, 0.f};

#pragma unroll
  for (int ks = 0; ks < 4; ++ks) {
    short8 af[4];
#pragma unroll
    for (int i = 0; i < 4; ++i)
      af[i] = *(short8*)&As[(i * 16 + lr) * 136 + ks * 32 + q * 8];
#pragma unroll
    for (int j = 0; j < 8; ++j) {
      short8 bf = *(const short8*)(Wt + (size_t)(colbase + j * 16 + lr) * 128 + ks * 32 + q * 8);
#pragma unroll
      for (int i = 0; i < 4; ++i)
        acc[i][j] = __builtin_amdgcn_mfma_f32_16x16x32_bf16(af[i], bf, acc[i][j], 0, 0, 0);
    }
  }
  __syncthreads();

  float bj[8];
#pragma unroll
  for (int j = 0; j < 8; ++j) bj[j] = bcat[colbase + j * 16 + lr];

  if (wave == 0 || wave == 3) {
    unsigned short* Ls16 = (unsigned short*)((wave == 0) ? L[1] : L[0]);
#pragma unroll
    for (int i = 0; i < 4; ++i)
#pragma unroll
      for (int r = 0; r < 4; ++r) {
        int row = i * 16 + q * 4 + r;
#pragma unroll
        for (int j = 0; j < 8; ++j)
          Ls16[row * 136 + j * 16 + lr] = f2bf(acc[i][j][r] + bj[j]);
      }
  } else {
    unsigned char* KLs = L[2];
    const int voff = (wave == 2) ? 2 : 0;
#pragma unroll
    for (int i = 0; i < 4; ++i)
#pragma unroll
      for (int r = 0; r < 4; ++r) {
        int row = i * 16 + q * 4 + r;
#pragma unroll
        for (int j = 0; j < 8; ++j) {
          int d = j * 16 + lr;
          KLs[row * 272 + 4 * (d >> 1) + voff + (d & 1)] = f2fp8(acc[i][j][r] + bj[j]);
        }
      }
  }
  __syncthreads();

#pragma unroll
  for (int p = 0; p < 4; ++p) {
    int f = tid + p * 256;
    int row = f >> 4, u = f & 15;
    int gr = bm + row;
    if (gr < M) {
      *(uint4*)(Q1b + (size_t)gr * 128 + u * 8) = *(uint4*)&((unsigned short*)L[1])[row * 136 + u * 8];
      *(uint4*)(KV8 + (size_t)gr * 256 + u * 16) = *(uint4*)&L[2][row * 272 + u * 16];
      *(uint4*)(SK1 + (size_t)gr * 128 + u * 8) = *(uint4*)&((unsigned short*)L[0])[row * 136 + u * 8];
    }
  }
}

// esrc stores src<<8 (byte offset into the 256B/node tables)
__global__ void bucket_csr(const int* __restrict__ ebuck, const int* __restrict__ boff,
                           int* __restrict__ rowptr, int* __restrict__ esrc, int N) {
  const int b = blockIdx.x;
  const int lo = boff[b], hi = boff[b + 1];
  const int cnt = hi - lo;
  __shared__ int hist[256];
  __shared__ int cur[256];
  __shared__ int sorted[BCAP];
  const int t = threadIdx.x;
  hist[t] = 0;
  __syncthreads();
  for (int i = t; i < cnt; i += 256) atomicAdd(&hist[ebuck[lo + i] & 255], 1);
  __syncthreads();
  int v = hist[t];
  sorted[t] = v;
  __syncthreads();
#pragma unroll
  for (int off = 1; off < 256; off <<= 1) {
    int u = (t >= off) ? sorted[t - off] : 0;
    __syncthreads();
    sorted[t] += u;
    __syncthreads();
  }
  int excl = sorted[t] - v;
  cur[t] = excl;
  int node = b * 256 + t;
  if (node <= N) rowptr[node] = lo + excl;
  __syncthreads();
  for (int i = t; i < cnt; i += 256) {
    int pk = ebuck[lo + i];
    int slot = atomicAdd(&cur[pk & 255], 1);
    if (slot < BCAP) sorted[slot] = pk;
    else esrc[lo + slot] = pk & 0xFFFFFF00;
  }
  __syncthreads();
  int lim = cnt < BCAP ? cnt : BCAP;
  for (int i = t; i < lim; i += 256) esrc[lo + i] = sorted[i] & 0xFFFFFF00;
}

// ---- gemm2: LDS-staged A (bf16); 128 cols -> C2 rows (256 B): [Q bf16 | KV fp8 itl | pad | H bf16] ----
__global__ __launch_bounds__(256) void gemm2(
    const unsigned short* __restrict__ Ab, const unsigned short* __restrict__ Wt,
    const float* __restrict__ bcat, unsigned char* __restrict__ C2b, int M) {
  __shared__ __align__(16) unsigned short As[64 * 136];
  __shared__ __align__(16) unsigned char Lsb[64 * 272];
  const int bm = blockIdx.x * 64;
  const int tid = threadIdx.x, wave = tid >> 6, lane = tid & 63;
  const int lr = lane & 15, q = lane >> 4;

#pragma unroll
  for (int p = 0; p < 4; ++p) {
    int f = tid + p * 256;
    int row = f >> 4, chunk = f & 15;
    int gm = bm + row; if (gm >= M) gm = 0;
    uint4 v = *(const uint4*)(Ab + (size_t)gm * 128 + chunk * 8);
    *(uint4*)&As[row * 136 + chunk * 8] = v;
  }
  __syncthreads();

  f32x4 acc[4][2];
#pragma unroll
  for (int i = 0; i < 4; ++i)
#pragma unroll
    for (int j = 0; j < 2; ++j) acc[i][j] = (f32x4){0.f, 0.f, 0.f, 0.f};

#pragma unroll
  for (int ks = 0; ks < 4; ++ks) {
    short8 af[4];
#pragma unroll
    for (int i = 0; i < 4; ++i)
      af[i] = *(short8*)&As[(i * 16 + lr) * 136 + ks * 32 + q * 8];
#pragma unroll
    for (int j = 0; j < 2; ++j) {
      short8 bf = *(const short8*)(Wt + (size_t)(wave * 32 + j * 16 + lr) * 128 + ks * 32 + q * 8);
#pragma unroll
      for (int i = 0; i < 4; ++i)
        acc[i][j] = __builtin_amdgcn_mfma_f32_16x16x32_bf16(af[i], bf, acc[i][j], 0, 0, 0);
    }
  }

  float bj[2];
#pragma unroll
  for (int j = 0; j < 2; ++j) bj[j] = bcat[wave * 32 + j * 16 + lr];
#pragma unroll
  for (int i = 0; i < 4; ++i)
#pragma unroll
    for (int r = 0; r < 4; ++r) {
      int row = i * 16 + q * 4 + r;
#pragma unroll
      for (int j = 0; j < 2; ++j) {
        int c = wave * 32 + j * 16 + lr;
        float val = acc[i][j][r] + bj[j];
        if (c < 32) {
          *(unsigned short*)&Lsb[row * 272 + 2 * c] = f2bf(val);
        } else if (c < 64) {
          int d = c - 32;
          Lsb[row * 272 + 64 + 4 * (d >> 1) + (d & 1)] = f2fp8(val);
        } else if (c < 96) {
          int d = c - 64;
          Lsb[row * 272 + 64 + 4 * (d >> 1) + 2 + (d & 1)] = f2fp8(val);
        } else {
          *(unsigned short*)&Lsb[row * 272 + 192 + 2 * (c - 96)] = f2bf(val);
        }
      }
    }
  __syncthreads();
#pragma unroll
  for (int p = 0; p < 16; ++p) {
    int idx = tid + p * 256;
    int row = idx >> 6, u = idx & 63;
    int gr = bm + row;
    if (gr < M) *(unsigned*)(C2b + (size_t)gr * 256 + u * 4) = *(const unsigned*)&Lsb[row * 272 + u * 4];
  }
}

// ================= fused aggregation: plain-exp softmax, fp8 K/V (interleaved) =================
// conv1: 32 lanes per edge; halves process disjoint edges; x8 main loop (4 edges/half).
__global__ void node_attn1(const int* __restrict__ rowptr, const int* __restrict__ esrc,
                           const unsigned short* __restrict__ Qb,
                           const unsigned char* __restrict__ KV8,
                           const unsigned short* __restrict__ SK, unsigned short* __restrict__ Hb,
                           int n) {
  int node = (blockIdx.x * blockDim.x + threadIdx.x) >> 6;
  int lane = threadIdx.x & 63;
  if (node >= n) return;
  const int half = lane >> 5, ll = lane & 31;
  const int r0 = rowptr[node], r1 = rowptr[node + 1];
  uint2 qq = *(const uint2*)(Qb + (size_t)node * 128 + ll * 4);
  const float q0 = bflo(qq.x), q1 = bfhi(qq.x), q2 = bflo(qq.y), q3 = bfhi(qq.y);
  float l = 0.f, a0 = 0.f, a1 = 0.f, a2 = 0.f, a3 = 0.f;
  const unsigned char* kvb = KV8 + ll * 8;
  int j = r0;
  for (; j + 8 <= r1; j += 8) {
    int e = j + half * 4;
    int s0 = esrc[e], s1 = esrc[e + 1], s2 = esrc[e + 2], s3 = esrc[e + 3];
    uint2 u0 = *(const uint2*)(kvb + s0);
    uint2 u1 = *(const uint2*)(kvb + s1);
    uint2 u2 = *(const uint2*)(kvb + s2);
    uint2 u3 = *(const uint2*)(kvb + s3);
    f32x2 k0a = fp8dec<false>(u0.x), k0b = fp8dec<false>(u0.y);
    f32x2 k1a = fp8dec<false>(u1.x), k1b = fp8dec<false>(u1.y);
    f32x2 k2a = fp8dec<false>(u2.x), k2b = fp8dec<false>(u2.y);
    f32x2 k3a = fp8dec<false>(u3.x), k3b = fp8dec<false>(u3.y);
    float d0 = q0 * k0a.x + q1 * k0a.y + q2 * k0b.x + q3 * k0b.y;
    float d1 = q0 * k1a.x + q1 * k1a.y + q2 * k1b.x + q3 * k1b.y;
    float d2 = q0 * k2a.x + q1 * k2a.y + q2 * k2b.x + q3 * k2b.y;
    float d3 = q0 * k3a.x + q1 * k3a.y + q2 * k3b.x + q3 * k3b.y;
#pragma unroll
    for (int msk = 1; msk <= 4; msk <<= 1) {
      d0 += __shfl_xor(d0, msk);
      d1 += __shfl_xor(d1, msk);
      d2 += __shfl_xor(d2, msk);
      d3 += __shfl_xor(d3, msk);
    }
    float p0 = __expf(d0), p1 = __expf(d1), p2 = __expf(d2), p3 = __expf(d3);
    l += (p0 + p1) + (p2 + p3);
    f32x2 v0a = fp8dec<true>(u0.x), v0b = fp8dec<true>(u0.y);
    f32x2 v1a = fp8dec<true>(u1.x), v1b = fp8dec<true>(u1.y);
    f32x2 v2a = fp8dec<true>(u2.x), v2b = fp8dec<true>(u2.y);
    f32x2 v3a = fp8dec<true>(u3.x), v3b = fp8dec<true>(u3.y);
    a0 += p0 * v0a.x + p1 * v1a.x + p2 * v2a.x + p3 * v3a.x;
    a1 += p0 * v0a.y + p1 * v1a.y + p2 * v2a.y + p3 * v3a.y;
    a2 += p0 * v0b.x + p1 * v1b.x + p2 * v2b.x + p3 * v3b.x;
    a3 += p0 * v0b.y + p1 * v1b.y + p2 * v2b.y + p3 * v3b.y;
  }
  for (; j < r1; j += 4) {  // masked tail, 2 edges/half per pass
    int eA = j + half * 2, eB = eA + 1;
    bool vA = eA < r1, vB = eB < r1;
    int sA = esrc[vA ? eA : r0];
    int sB = esrc[vB ? eB : r0];
    uint2 ua = *(const uint2*)(kvb + sA);
    uint2 ub = *(const uint2*)(kvb + sB);
    f32x2 ka1 = fp8dec<false>(ua.x), ka2 = fp8dec<false>(ua.y);
    f32x2 kb1 = fp8dec<false>(ub.x), kb2 = fp8dec<false>(ub.y);
    float dA = q0 * ka1.x + q1 * ka1.y + q2 * ka2.x + q3 * ka2.y;
    float dB = q0 * kb1.x + q1 * kb1.y + q2 * kb2.x + q3 * kb2.y;
#pragma unroll
    for (int msk = 1; msk <= 4; msk <<= 1) {
      dA += __shfl_xor(dA, msk);
      dB += __shfl_xor(dB, msk);
    }
    float pA = vA ? __expf(dA) : 0.f;
    float pB = vB ? __expf(dB) : 0.f;
    l += pA + pB;
    f32x2 va1 = fp8dec<true>(ua.x), va2 = fp8dec<true>(ua.y);
    f32x2 vb1 = fp8dec<true>(ub.x), vb2 = fp8dec<true>(ub.y);
    a0 += pA * va1.x + pB * vb1.x;
    a1 += pA * va1.y + pB * vb1.y;
    a2 += pA * va2.x + pB * vb2.x;
    a3 += pA * va2.y + pB * vb2.y;
  }
  l  += __shfl_xor(l, 32);
  a0 += __shfl_xor(a0, 32);
  a1 += __shfl_xor(a1, 32);
  a2 += __shfl_xor(a2, 32);
  a3 += __shfl_xor(a3, 32);
  float inv = (l > 0.f) ? 1.f / l : 0.f;
  if (half == 0) {
    uint2 sk = *(const uint2*)(SK + (size_t)node * 128 + ll * 4);
    float o0 = fmaxf(bflo(sk.x) + a0 * inv, 0.f);
    float o1 = fmaxf(bfhi(sk.x) + a1 * inv, 0.f);
    float o2 = fmaxf(bflo(sk.y) + a2 * inv, 0.f);
    float o3 = fmaxf(bfhi(sk.y) + a3 * inv, 0.f);
    uint2 hb;
    hb.x = ((unsigned)f2bf(o1) << 16) | (unsigned)f2bf(o0);
    hb.y = ((unsigned)f2bf(o3) << 16) | (unsigned)f2bf(o2);
    *(uint2*)(Hb + (size_t)node * 128 + ll * 4) = hb;
  }
}

// conv2 + fused relu/mean/Wo-dot: 16 lanes per edge (4 groups); x8 main loop; plain exp.
__global__ void node_attn2(const int* __restrict__ rowptr, const int* __restrict__ esrc,
                           const unsigned char* __restrict__ C2b, const float* __restrict__ Wo,
                           float* __restrict__ pblock, int n) {
  __shared__ float ps[4];
  int node = (blockIdx.x * blockDim.x + threadIdx.x) >> 6;
  int lane = threadIdx.x & 63;
  int wave = threadIdx.x >> 6;
  const int g = lane >> 4, gl = lane & 15;
  float t = 0.f;
  if (node < n) {
    const int r0 = rowptr[node], r1 = rowptr[node + 1];
    unsigned qu = *(const unsigned*)(C2b + (size_t)node * 256 + gl * 4);
    const float q0 = bflo(qu), q1 = bfhi(qu);
    float l = 0.f, a0 = 0.f, a1 = 0.f;
    const unsigned char* kvb = C2b + 64 + gl * 4;
    int j = r0;
    for (; j + 8 <= r1; j += 8) {
      int e = j + g * 2;
      int s0 = esrc[e], s1 = esrc[e + 1];
      unsigned u0 = *(const unsigned*)(kvb + s0);
      unsigned u1 = *(const unsigned*)(kvb + s1);
      f32x2 k0 = fp8dec<false>(u0), k1 = fp8dec<false>(u1);
      float d0 = q0 * k0.x + q1 * k0.y;
      float d1 = q0 * k1.x + q1 * k1.y;
#pragma unroll
      for (int msk = 1; msk <= 8; msk <<= 1) {
        d0 += __shfl_xor(d0, msk);
        d1 += __shfl_xor(d1, msk);
      }
      float p0 = __expf(d0), p1 = __expf(d1);
      l += p0 + p1;
      f32x2 v0 = fp8dec<true>(u0), v1 = fp8dec<true>(u1);
      a0 += p0 * v0.x + p1 * v1.x;
      a1 += p0 * v0.y + p1 * v1.y;
    }
    for (; j < r1; j += 4) {
      bool v = (j + g) < r1;
      int s = esrc[v ? j + g : r0];
      unsigned u = *(const unsigned*)(kvb + s);
      f32x2 kd = fp8dec<false>(u);
      float d = q0 * kd.x + q1 * kd.y;
#pragma unroll
      for (int msk = 1; msk <= 8; msk <<= 1) d += __shfl_xor(d, msk);
      float p = v ? __expf(d) : 0.f;
      l += p;
      f32x2 vd = fp8dec<true>(u);
      a0 += p * vd.x;
      a1 += p * vd.y;
    }
#pragma unroll
    for (int msk = 16; msk <= 32; msk <<= 1) {
      l  += __shfl_xor(l, msk);
      a0 += __shfl_xor(a0, msk);
      a1 += __shfl_xor(a1, msk);
    }
    float inv = (l > 0.f) ? 1.f / l : 0.f;
    unsigned hu = *(const unsigned*)(C2b + (size_t)node * 256 + 192 + gl * 4);
    float o0 = fmaxf(bflo(hu) + a0 * inv, 0.f);
    float o1 = fmaxf(bfhi(hu) + a1 * inv, 0.f);
    t = o0 * Wo[2 * gl] + o1 * Wo[2 * gl + 1];
#pragma unroll
    for (int msk = 1; msk <= 8; msk <<= 1) t += __shfl_xor(t, msk);
  }
  if (lane == 0) ps[wave] = t;
  __syncthreads();
  if (threadIdx.x == 0) pblock[blockIdx.x] = ps[0] + ps[1] + ps[2] + ps[3];
}

// ---------------- final: sum per-block partials, scale, bias ----------------
__global__ void final_out(const float* __restrict__ pblock, const float* __restrict__ bo,
                          float* __restrict__ out, int nb, float invN) {
  __shared__ float s[256];
  float acc = 0.f;
  for (int i = threadIdx.x; i < nb; i += 256) acc += pblock[i];
  s[threadIdx.x] = acc;
  __syncthreads();
  for (int off = 128; off >= 1; off >>= 1) {
    if (threadIdx.x < off) s[threadIdx.x] += s[threadIdx.x + off];
    __syncthreads();
  }
  if (threadIdx.x == 0) out[0] = s[0] * invN + bo[0];
}

extern "C" void kernel_launch(void* const* d_in, const int* in_sizes, int n_in,
                              void* d_out, int out_size, void* d_ws, size_t ws_size,
                              hipStream_t stream) {
  const float* x   = (const float*)d_in[0];
  const int*   ei  = (const int*)d_in[1];  // [2, E]: row 0 = src, row 1 = dst
  const float* Wq1 = (const float*)d_in[2];  const float* bq1 = (const float*)d_in[3];
  const float* Wk1 = (const float*)d_in[4];  const float* bk1 = (const float*)d_in[5];
  const float* Wv1 = (const float*)d_in[6];  const float* bv1 = (const float*)d_in[7];
  const float* Ws1 = (const float*)d_in[8];  const float* bs1 = (const float*)d_in[9];
  const float* Wq2 = (const float*)d_in[10]; const float* bq2 = (const float*)d_in[11];
  const float* Wk2 = (const float*)d_in[12]; const float* bk2 = (const float*)d_in[13];
  const float* Wv2 = (const float*)d_in[14]; const float* bv2 = (const float*)d_in[15];
  const float* Ws2 = (const float*)d_in[16]; const float* bs2 = (const float*)d_in[17];
  const float* Wo  = (const float*)d_in[18]; const float* bo  = (const float*)d_in[19];

  char* ws = (char*)d_ws;
  const int N = N_NODES, E = N_EDGES;
  const int GB = (N + 63) / 64;
  const int EBH = (E + 4095) / 4096;   // histogram chunks (prep)
  const int EBS = (E + 2047) / 2048;   // scatter chunks (finer for latency)
  const int AB = (N * 64) / 256;       // 12500 attn blocks

  // buffers
  unsigned short* Q1b = (unsigned short*)(ws + 0);          // N*128 bf16 (pre-scaled)
  unsigned short* SK1 = (unsigned short*)(ws + 12800000);   // N*128 bf16
  unsigned char*  KV1 = (unsigned char*)(ws + 25600000);    // N*256 fp8 interleaved
  unsigned short* H1b = (unsigned short*)(ws + 51200000);   // N*128 bf16
  unsigned char*  C2  = (unsigned char*)(ws + 64000000);    // N*256 bytes [Q|KV8|pad|H]
  // CSR + weights + misc
  int* rowptr = (int*)(ws + 89600000);                      // N+1
  int* esrc   = (int*)(ws + 89900032);                      // E (byte offsets, src<<8)
  int* bhist  = (int*)(ws + 93100032);                      // NBK
  int* boff   = (int*)(ws + 93101056);                      // NBK+1
  int* bcur   = (int*)(ws + 93102080);                      // NBK
  unsigned short* Wt1   = (unsigned short*)(ws + 93103104);   // 512x128 bf16
  unsigned short* Wt2   = (unsigned short*)(ws + 93234176);   // 128x128 bf16
  float*          bcat1 = (float*)(ws + 93266944);
  float*          bcat2 = (float*)(ws + 93268992);
  float*          pblock = (float*)(ws + 93269504);         // 12500 floats
  int*            ebuck = (int*)(ws + 93319552);            // E * 4B packed

  float* out = (float*)d_out;

  dim3 blk(256);

  hipMemsetAsync(bhist, 0, NBK * sizeof(int), stream);

  // ---- fused prep: weights + bucket histogram ----
  prep_fused<<<dim3(W1_B + W2_B + EBH), blk, 0, stream>>>(
      Wq1, Wk1, Wv1, Ws1, bq1, bk1, bv1, bs1,
      Wq2, Wk2, Wv2, Ws2, bq2, bk2, bv2, bs2,
      Wt1, bcat1, Wt2, bcat2, ei, bhist, E);

  // ---- bucket scan ----
  bucket_scan<<<dim3(1), blk, 0, stream>>>(bhist, boff, bcur);

  // ---- FUSED: edge scatter (2048-edge chunks) + conv1 GEMM (64x512) ----
  scatter_gemm1<<<dim3(EBS + GB), blk, 0, stream>>>(
      ei, bcur, ebuck, E, EBS, x, Wt1, bcat1, Q1b, SK1, KV1, N);

  // ---- per-bucket CSR finalize ----
  bucket_csr<<<dim3(NBK), blk, 0, stream>>>(ebuck, boff, rowptr, esrc, N);

  // ---- conv1 fused attention + skip + relu -> bf16 ----
  node_attn1<<<dim3(AB), blk, 0, stream>>>(rowptr, esrc, Q1b, KV1, SK1, H1b, N);

  // ---- conv2 GEMM (fused Q|KV8|H rows) ----
  gemm2<<<dim3(GB), blk, 0, stream>>>(H1b, Wt2, bcat2, C2, N);

  // ---- conv2 attention + fused relu/mean/Wo-dot -> per-block partials ----
  node_attn2<<<dim3(AB), blk, 0, stream>>>(rowptr, esrc, C2, Wo, pblock, N);

  // ---- final reduce ----
  final_out<<<dim3(1), blk, 0, stream>>>(pblock, bo, out, AB, 1.0f / (float)N);
}

// Round 18
// 250.560 us; speedup vs baseline: 1.0208x; 1.0208x over previous
//
#include <hip/hip_runtime.h>
#include <math.h>

#define N_NODES 50000
#define N_EDGES 800000
#define NBK 196          // dst buckets of 256 nodes: bucket = dst >> 8
#define BCAP 6144        // max edges per bucket handled in LDS (mean 4082, sigma 64)

typedef short short8 __attribute__((ext_vector_type(8)));
typedef float f32x4 __attribute__((ext_vector_type(4)));
typedef float f32x2 __attribute__((ext_vector_type(2)));

// ---------------- bf16 / fp8 helpers ----------------
__device__ inline unsigned short f2bf(float v) {
  unsigned u = __float_as_uint(v);
  u += 0x7FFFu + ((u >> 16) & 1u);  // round-to-nearest-even
  return (unsigned short)(u >> 16);
}
__device__ inline float bf2f(unsigned short b) {
  return __uint_as_float(((unsigned)b) << 16);
}
__device__ inline float bflo(unsigned u) { return __uint_as_float(u << 16); }
__device__ inline float bfhi(unsigned u) { return __uint_as_float(u & 0xFFFF0000u); }
// fp8 e4m3 (OCP on gfx950); decode selector must be an immediate -> template param.
__device__ inline unsigned char f2fp8(float v) {
  return (unsigned char)(__builtin_amdgcn_cvt_pk_fp8_f32(v, 0.f, 0, false) & 0xFF);
}
template <bool HI>
__device__ inline f32x2 fp8dec(unsigned u) {
  return __builtin_amdgcn_cvt_pk_f32_fp8(u, HI);
}

#define SCL 0.17677669529663687f   // 1/sqrt(32), folded into Wq/bq at prep

// ---------------- fused prep: weight concat/transpose + bucket histogram ----------------
#define W1_B 256      // 512*128 / 256
#define W2_B 64       // 128*128 / 256
__global__ void prep_fused(const float* __restrict__ Wq1, const float* __restrict__ Wk1,
                           const float* __restrict__ Wv1, const float* __restrict__ Ws1,
                           const float* __restrict__ bq1, const float* __restrict__ bk1,
                           const float* __restrict__ bv1, const float* __restrict__ bs1,
                           const float* __restrict__ Wq2, const float* __restrict__ Wk2,
                           const float* __restrict__ Wv2, const float* __restrict__ Ws2,
                           const float* __restrict__ bq2, const float* __restrict__ bk2,
                           const float* __restrict__ bv2, const float* __restrict__ bs2,
                           unsigned short* __restrict__ Wt1, float* __restrict__ bcat1,
                           unsigned short* __restrict__ Wt2, float* __restrict__ bcat2,
                           const int* __restrict__ ei, int* __restrict__ bhist, int E) {
  const int b = blockIdx.x, tid = threadIdx.x;
  if (b < W1_B) {
    int i = b * 256 + tid;   // over 512*128
    int c = i >> 7, k = i & 127;
    int mi = c >> 7, lc = c & 127;
    const float* W = (mi == 0) ? Wq1 : (mi == 1) ? Wk1 : (mi == 2) ? Wv1 : Ws1;
    float scl = (mi == 0) ? SCL : 1.f;
    Wt1[i] = f2bf(W[(size_t)k * 128 + lc] * scl);
    if (i < 512) {
      int bm = i >> 7, bl = i & 127;
      const float* bb = (bm == 0) ? bq1 : (bm == 1) ? bk1 : (bm == 2) ? bv1 : bs1;
      bcat1[i] = bb[bl] * ((bm == 0) ? SCL : 1.f);
    }
  } else if (b < W1_B + W2_B) {
    int i = (b - W1_B) * 256 + tid;  // over 128*128
    int c = i >> 7, k = i & 127;
    int mi = c >> 5, lc = c & 31;
    const float* W = (mi == 0) ? Wq2 : (mi == 1) ? Wk2 : (mi == 2) ? Wv2 : Ws2;
    float scl = (mi == 0) ? SCL : 1.f;
    Wt2[i] = f2bf(W[(size_t)k * 32 + lc] * scl);
    if (i < 128) {
      int bm = i >> 5, bl = i & 31;
      const float* bb = (bm == 0) ? bq2 : (bm == 1) ? bk2 : (bm == 2) ? bv2 : bs2;
      bcat2[i] = bb[bl] * ((bm == 0) ? SCL : 1.f);
    }
  } else {
    __shared__ int h[NBK];
    for (int i = tid; i < NBK; i += 256) h[i] = 0;
    __syncthreads();
    int e = (b - W1_B - W2_B) * 4096 + tid;
#pragma unroll
    for (int p = 0; p < 16; ++p, e += 256)
      if (e < E) atomicAdd(&h[ei[E + e] >> 8], 1);
    __syncthreads();
    for (int i = tid; i < NBK; i += 256)
      if (h[i]) atomicAdd(&bhist[i], h[i]);
  }
}

// ================= bucket scan =================
__global__ void bucket_scan(const int* __restrict__ bhist, int* __restrict__ boff,
                            int* __restrict__ bcur) {
  __shared__ int s[256];
  int t = threadIdx.x;
  int v = (t < NBK) ? bhist[t] : 0;
  s[t] = v;
  __syncthreads();
#pragma unroll
  for (int off = 1; off < 256; off <<= 1) {
    int u = (t >= off) ? s[t - off] : 0;
    __syncthreads();
    s[t] += u;
    __syncthreads();
  }
  if (t < NBK) {
    int excl = s[t] - v;
    boff[t] = excl;
    bcur[t] = excl;
  }
  if (t == NBK - 1) boff[NBK] = s[t];
}

// ================= FUSED: bucket_scatter (blocks [0,EB)) + conv1 GEMM (blocks [EB,EB+GB)) ====
// GEMM block = 64 rows x ALL 512 cols; A staged from fp32 x (bf16 in-flight);
// wave0->Q(bf16), wave1->K(fp8), wave2->V(fp8), wave3->SK(bf16).
// KV fp8 row (256 B/node) INTERLEAVED: byte 4t+{0,1} = K[2t,2t+1], 4t+{2,3} = V[2t,2t+1].
// ebuck packed: (src<<8) | (dst & 255).
__global__ __launch_bounds__(256) void scatter_gemm1(
    const int* __restrict__ ei, int* __restrict__ bcur, int* __restrict__ ebuck, int E, int EB,
    const float* __restrict__ X, const unsigned short* __restrict__ Wt,
    const float* __restrict__ bcat, unsigned short* __restrict__ Q1b,
    unsigned short* __restrict__ SK1, unsigned char* __restrict__ KV8, int M) {
  __shared__ __align__(16) unsigned char L[3][64 * 272];  // 52.2 KB
  const int tid = threadIdx.x;

  if ((int)blockIdx.x < EB) {
    // ---------- scatter path: 4096 edges, 16 per thread ----------
    int* lh = (int*)L[0];
    for (int i = tid; i < NBK; i += 256) lh[i] = 0;
    __syncthreads();
    const int e0 = blockIdx.x * 4096;
    int pks[16], bks[16];
#pragma unroll
    for (int p = 0; p < 16; ++p) {
      int e = e0 + p * 256 + tid;
      if (e < E) {
        int src = ei[e], dst = ei[E + e];
        pks[p] = (src << 8) | (dst & 255);
        bks[p] = dst >> 8;
        atomicAdd(&lh[bks[p]], 1);
      } else bks[p] = -1;
    }
    __syncthreads();
    for (int i = tid; i < NBK; i += 256)
      if (lh[i]) lh[i] = atomicAdd(&bcur[i], lh[i]);
    __syncthreads();
#pragma unroll
    for (int p = 0; p < 16; ++p) {
      if (bks[p] >= 0) {
        int slot = atomicAdd(&lh[bks[p]], 1);
        ebuck[slot] = pks[p];
      }
    }
    return;
  }

  // ---------- GEMM path ----------
  unsigned short* As = (unsigned short*)L[0];             // stride 136 shorts
  const int bm = (blockIdx.x - EB) * 64;
  const int wave = tid >> 6, lane = tid & 63;
  const int lr = lane & 15, q = lane >> 4;

#pragma unroll
  for (int p = 0; p < 8; ++p) {
    int f = tid + p * 256;          // 0..2047 float4s
    int row = f >> 5, c4 = f & 31;
    int gm = bm + row; if (gm >= M) gm = 0;
    float4 v = *(const float4*)(X + (size_t)gm * 128 + c4 * 4);
    ushort4 o;
    o.x = f2bf(v.x); o.y = f2bf(v.y); o.z = f2bf(v.z); o.w = f2bf(v.w);
    *(ushort4*)&As[row * 136 + c4 * 4] = o;
  }
  __syncthreads();

  const int colbase = wave * 128;
  f32x4 acc[4][8];
#pragma unroll
  for (int i = 0; i < 4; ++i)
#pragma unroll
    for (int j = 0; j < 8; ++j) acc[i][j] = (f32x4){0.f, 0.f, 0.f, 0.f};

#pragma unroll
  for (int ks = 0; ks < 4; ++ks) {
    short8 af[4];
#pragma unroll
    for (int i = 0; i < 4; ++i)
      af[i] = *(short8*)&As[(i * 16 + lr) * 136 + ks * 32 + q * 8];
#pragma unroll
    for (int j = 0; j < 8; ++j) {
      short8 bf = *(const short8*)(Wt + (size_t)(colbase + j * 16 + lr) * 128 + ks * 32 + q * 8);
#pragma unroll
      for (int i = 0; i < 4; ++i)
        acc[i][j] = __builtin_amdgcn_mfma_f32_16x16x32_bf16(af[i], bf, acc[i][j], 0, 0, 0);
    }
  }
  __syncthreads();

  float bj[8];
#pragma unroll
  for (int j = 0; j < 8; ++j) bj[j] = bcat[colbase + j * 16 + lr];

  if (wave == 0 || wave == 3) {
    unsigned short* Ls16 = (unsigned short*)((wave == 0) ? L[1] : L[0]);
#pragma unroll
    for (int i = 0; i < 4; ++i)
#pragma unroll
      for (int r = 0; r < 4; ++r) {
        int row = i * 16 + q * 4 + r;
#pragma unroll
        for (int j = 0; j < 8; ++j)
          Ls16[row * 136 + j * 16 + lr] = f2bf(acc[i][j][r] + bj[j]);
      }
  } else {
    unsigned char* KLs = L[2];
    const int voff = (wave == 2) ? 2 : 0;
#pragma unroll
    for (int i = 0; i < 4; ++i)
#pragma unroll
      for (int r = 0; r < 4; ++r) {
        int row = i * 16 + q * 4 + r;
#pragma unroll
        for (int j = 0; j < 8; ++j) {
          int d = j * 16 + lr;
          KLs[row * 272 + 4 * (d >> 1) + voff + (d & 1)] = f2fp8(acc[i][j][r] + bj[j]);
        }
      }
  }
  __syncthreads();

#pragma unroll
  for (int p = 0; p < 4; ++p) {
    int f = tid + p * 256;
    int row = f >> 4, u = f & 15;
    int gr = bm + row;
    if (gr < M) {
      *(uint4*)(Q1b + (size_t)gr * 128 + u * 8) = *(uint4*)&((unsigned short*)L[1])[row * 136 + u * 8];
      *(uint4*)(KV8 + (size_t)gr * 256 + u * 16) = *(uint4*)&L[2][row * 272 + u * 16];
      *(uint4*)(SK1 + (size_t)gr * 128 + u * 8) = *(uint4*)&((unsigned short*)L[0])[row * 136 + u * 8];
    }
  }
}

// esrc stores src<<8 (byte offset into the 256B/node tables)
__global__ void bucket_csr(const int* __restrict__ ebuck, const int* __restrict__ boff,
                           int* __restrict__ rowptr, int* __restrict__ esrc, int N) {
  const int b = blockIdx.x;
  const int lo = boff[b], hi = boff[b + 1];
  const int cnt = hi - lo;
  __shared__ int hist[256];
  __shared__ int cur[256];
  __shared__ int sorted[BCAP];
  const int t = threadIdx.x;
  hist[t] = 0;
  __syncthreads();
  for (int i = t; i < cnt; i += 256) atomicAdd(&hist[ebuck[lo + i] & 255], 1);
  __syncthreads();
  int v = hist[t];
  sorted[t] = v;
  __syncthreads();
#pragma unroll
  for (int off = 1; off < 256; off <<= 1) {
    int u = (t >= off) ? sorted[t - off] : 0;
    __syncthreads();
    sorted[t] += u;
    __syncthreads();
  }
  int excl = sorted[t] - v;
  cur[t] = excl;
  int node = b * 256 + t;
  if (node <= N) rowptr[node] = lo + excl;
  __syncthreads();
  for (int i = t; i < cnt; i += 256) {
    int pk = ebuck[lo + i];
    int slot = atomicAdd(&cur[pk & 255], 1);
    if (slot < BCAP) sorted[slot] = pk;
    else esrc[lo + slot] = pk & 0xFFFFFF00;
  }
  __syncthreads();
  int lim = cnt < BCAP ? cnt : BCAP;
  for (int i = t; i < lim; i += 256) esrc[lo + i] = sorted[i] & 0xFFFFFF00;
}

// ---- gemm2: LDS-staged A (bf16); 128 cols -> C2 rows (256 B): [Q bf16 | KV fp8 itl | pad | H bf16] ----
__global__ __launch_bounds__(256) void gemm2(
    const unsigned short* __restrict__ Ab, const unsigned short* __restrict__ Wt,
    const float* __restrict__ bcat, unsigned char* __restrict__ C2b, int M) {
  __shared__ __align__(16) unsigned short As[64 * 136];
  __shared__ __align__(16) unsigned char Lsb[64 * 272];
  const int bm = blockIdx.x * 64;
  const int tid = threadIdx.x, wave = tid >> 6, lane = tid & 63;
  const int lr = lane & 15, q = lane >> 4;

#pragma unroll
  for (int p = 0; p < 4; ++p) {
    int f = tid + p * 256;
    int row = f >> 4, chunk = f & 15;
    int gm = bm + row; if (gm >= M) gm = 0;
    uint4 v = *(const uint4*)(Ab + (size_t)gm * 128 + chunk * 8);
    *(uint4*)&As[row * 136 + chunk * 8] = v;
  }
  __syncthreads();

  f32x4 acc[4][2];
#pragma unroll
  for (int i = 0; i < 4; ++i)
#pragma unroll
    for (int j = 0; j < 2; ++j) acc[i][j] = (f32x4){0.f, 0.f, 0.f, 0.f};

#pragma unroll
  for (int ks = 0; ks < 4; ++ks) {
    short8 af[4];
#pragma unroll
    for (int i = 0; i < 4; ++i)
      af[i] = *(short8*)&As[(i * 16 + lr) * 136 + ks * 32 + q * 8];
#pragma unroll
    for (int j = 0; j < 2; ++j) {
      short8 bf = *(const short8*)(Wt + (size_t)(wave * 32 + j * 16 + lr) * 128 + ks * 32 + q * 8);
#pragma unroll
      for (int i = 0; i < 4; ++i)
        acc[i][j] = __builtin_amdgcn_mfma_f32_16x16x32_bf16(af[i], bf, acc[i][j], 0, 0, 0);
    }
  }

  float bj[2];
#pragma unroll
  for (int j = 0; j < 2; ++j) bj[j] = bcat[wave * 32 + j * 16 + lr];
#pragma unroll
  for (int i = 0; i < 4; ++i)
#pragma unroll
    for (int r = 0; r < 4; ++r) {
      int row = i * 16 + q * 4 + r;
#pragma unroll
      for (int j = 0; j < 2; ++j) {
        int c = wave * 32 + j * 16 + lr;
        float val = acc[i][j][r] + bj[j];
        if (c < 32) {
          *(unsigned short*)&Lsb[row * 272 + 2 * c] = f2bf(val);
        } else if (c < 64) {
          int d = c - 32;
          Lsb[row * 272 + 64 + 4 * (d >> 1) + (d & 1)] = f2fp8(val);
        } else if (c < 96) {
          int d = c - 64;
          Lsb[row * 272 + 64 + 4 * (d >> 1) + 2 + (d & 1)] = f2fp8(val);
        } else {
          *(unsigned short*)&Lsb[row * 272 + 192 + 2 * (c - 96)] = f2bf(val);
        }
      }
    }
  __syncthreads();
#pragma unroll
  for (int p = 0; p < 16; ++p) {
    int idx = tid + p * 256;
    int row = idx >> 6, u = idx & 63;
    int gr = bm + row;
    if (gr < M) *(unsigned*)(C2b + (size_t)gr * 256 + u * 4) = *(const unsigned*)&Lsb[row * 272 + u * 4];
  }
}

// ================= fused aggregation: plain-exp softmax, fp8 K/V (interleaved) =================
// conv1: 32 lanes per edge; halves process disjoint edges; x8 main loop (4 edges/half).
__global__ void node_attn1(const int* __restrict__ rowptr, const int* __restrict__ esrc,
                           const unsigned short* __restrict__ Qb,
                           const unsigned char* __restrict__ KV8,
                           const unsigned short* __restrict__ SK, unsigned short* __restrict__ Hb,
                           int n) {
  int node = (blockIdx.x * blockDim.x + threadIdx.x) >> 6;
  int lane = threadIdx.x & 63;
  if (node >= n) return;
  const int half = lane >> 5, ll = lane & 31;
  const int r0 = rowptr[node], r1 = rowptr[node + 1];
  uint2 qq = *(const uint2*)(Qb + (size_t)node * 128 + ll * 4);
  const float q0 = bflo(qq.x), q1 = bfhi(qq.x), q2 = bflo(qq.y), q3 = bfhi(qq.y);
  float l = 0.f, a0 = 0.f, a1 = 0.f, a2 = 0.f, a3 = 0.f;
  const unsigned char* kvb = KV8 + ll * 8;
  int j = r0;
  for (; j + 8 <= r1; j += 8) {
    int e = j + half * 4;
    int s0 = esrc[e], s1 = esrc[e + 1], s2 = esrc[e + 2], s3 = esrc[e + 3];
    uint2 u0 = *(const uint2*)(kvb + s0);
    uint2 u1 = *(const uint2*)(kvb + s1);
    uint2 u2 = *(const uint2*)(kvb + s2);
    uint2 u3 = *(const uint2*)(kvb + s3);
    f32x2 k0a = fp8dec<false>(u0.x), k0b = fp8dec<false>(u0.y);
    f32x2 k1a = fp8dec<false>(u1.x), k1b = fp8dec<false>(u1.y);
    f32x2 k2a = fp8dec<false>(u2.x), k2b = fp8dec<false>(u2.y);
    f32x2 k3a = fp8dec<false>(u3.x), k3b = fp8dec<false>(u3.y);
    float d0 = q0 * k0a.x + q1 * k0a.y + q2 * k0b.x + q3 * k0b.y;
    float d1 = q0 * k1a.x + q1 * k1a.y + q2 * k1b.x + q3 * k1b.y;
    float d2 = q0 * k2a.x + q1 * k2a.y + q2 * k2b.x + q3 * k2b.y;
    float d3 = q0 * k3a.x + q1 * k3a.y + q2 * k3b.x + q3 * k3b.y;
#pragma unroll
    for (int msk = 1; msk <= 4; msk <<= 1) {
      d0 += __shfl_xor(d0, msk);
      d1 += __shfl_xor(d1, msk);
      d2 += __shfl_xor(d2, msk);
      d3 += __shfl_xor(d3, msk);
    }
    float p0 = __expf(d0), p1 = __expf(d1), p2 = __expf(d2), p3 = __expf(d3);
    l += (p0 + p1) + (p2 + p3);
    f32x2 v0a = fp8dec<true>(u0.x), v0b = fp8dec<true>(u0.y);
    f32x2 v1a = fp8dec<true>(u1.x), v1b = fp8dec<true>(u1.y);
    f32x2 v2a = fp8dec<true>(u2.x), v2b = fp8dec<true>(u2.y);
    f32x2 v3a = fp8dec<true>(u3.x), v3b = fp8dec<true>(u3.y);
    a0 += p0 * v0a.x + p1 * v1a.x + p2 * v2a.x + p3 * v3a.x;
    a1 += p0 * v0a.y + p1 * v1a.y + p2 * v2a.y + p3 * v3a.y;
    a2 += p0 * v0b.x + p1 * v1b.x + p2 * v2b.x + p3 * v3b.x;
    a3 += p0 * v0b.y + p1 * v1b.y + p2 * v2b.y + p3 * v3b.y;
  }
  for (; j < r1; j += 4) {  // masked tail, 2 edges/half per pass
    int eA = j + half * 2, eB = eA + 1;
    bool vA = eA < r1, vB = eB < r1;
    int sA = esrc[vA ? eA : r0];
    int sB = esrc[vB ? eB : r0];
    uint2 ua = *(const uint2*)(kvb + sA);
    uint2 ub = *(const uint2*)(kvb + sB);
    f32x2 ka1 = fp8dec<false>(ua.x), ka2 = fp8dec<false>(ua.y);
    f32x2 kb1 = fp8dec<false>(ub.x), kb2 = fp8dec<false>(ub.y);
    float dA = q0 * ka1.x + q1 * ka1.y + q2 * ka2.x + q3 * ka2.y;
    float dB = q0 * kb1.x + q1 * kb1.y + q2 * kb2.x + q3 * kb2.y;
#pragma unroll
    for (int msk = 1; msk <= 4; msk <<= 1) {
      dA += __shfl_xor(dA, msk);
      dB += __shfl_xor(dB, msk);
    }
    float pA = vA ? __expf(dA) : 0.f;
    float pB = vB ? __expf(dB) : 0.f;
    l += pA + pB;
    f32x2 va1 = fp8dec<true>(ua.x), va2 = fp8dec<true>(ua.y);
    f32x2 vb1 = fp8dec<true>(ub.x), vb2 = fp8dec<true>(ub.y);
    a0 += pA * va1.x + pB * vb1.x;
    a1 += pA * va1.y + pB * vb1.y;
    a2 += pA * va2.x + pB * vb2.x;
    a3 += pA * va2.y + pB * vb2.y;
  }
  l  += __shfl_xor(l, 32);
  a0 += __shfl_xor(a0, 32);
  a1 += __shfl_xor(a1, 32);
  a2 += __shfl_xor(a2, 32);
  a3 += __shfl_xor(a3, 32);
  float inv = (l > 0.f) ? 1.f / l : 0.f;
  if (half == 0) {
    uint2 sk = *(const uint2*)(SK + (size_t)node * 128 + ll * 4);
    float o0 = fmaxf(bflo(sk.x) + a0 * inv, 0.f);
    float o1 = fmaxf(bfhi(sk.x) + a1 * inv, 0.f);
    float o2 = fmaxf(bflo(sk.y) + a2 * inv, 0.f);
    float o3 = fmaxf(bfhi(sk.y) + a3 * inv, 0.f);
    uint2 hb;
    hb.x = ((unsigned)f2bf(o1) << 16) | (unsigned)f2bf(o0);
    hb.y = ((unsigned)f2bf(o3) << 16) | (unsigned)f2bf(o2);
    *(uint2*)(Hb + (size_t)node * 128 + ll * 4) = hb;
  }
}

// conv2 + fused relu/mean/Wo-dot: 16 lanes per edge (4 groups); x8 main loop; plain exp.
__global__ void node_attn2(const int* __restrict__ rowptr, const int* __restrict__ esrc,
                           const unsigned char* __restrict__ C2b, const float* __restrict__ Wo,
                           float* __restrict__ pblock, int n) {
  __shared__ float ps[4];
  int node = (blockIdx.x * blockDim.x + threadIdx.x) >> 6;
  int lane = threadIdx.x & 63;
  int wave = threadIdx.x >> 6;
  const int g = lane >> 4, gl = lane & 15;
  float t = 0.f;
  if (node < n) {
    const int r0 = rowptr[node], r1 = rowptr[node + 1];
    unsigned qu = *(const unsigned*)(C2b + (size_t)node * 256 + gl * 4);
    const float q0 = bflo(qu), q1 = bfhi(qu);
    float l = 0.f, a0 = 0.f, a1 = 0.f;
    const unsigned char* kvb = C2b + 64 + gl * 4;
    int j = r0;
    for (; j + 8 <= r1; j += 8) {
      int e = j + g * 2;
      int s0 = esrc[e], s1 = esrc[e + 1];
      unsigned u0 = *(const unsigned*)(kvb + s0);
      unsigned u1 = *(const unsigned*)(kvb + s1);
      f32x2 k0 = fp8dec<false>(u0), k1 = fp8dec<false>(u1);
      float d0 = q0 * k0.x + q1 * k0.y;
      float d1 = q0 * k1.x + q1 * k1.y;
#pragma unroll
      for (int msk = 1; msk <= 8; msk <<= 1) {
        d0 += __shfl_xor(d0, msk);
        d1 += __shfl_xor(d1, msk);
      }
      float p0 = __expf(d0), p1 = __expf(d1);
      l += p0 + p1;
      f32x2 v0 = fp8dec<true>(u0), v1 = fp8dec<true>(u1);
      a0 += p0 * v0.x + p1 * v1.x;
      a1 += p0 * v0.y + p1 * v1.y;
    }
    for (; j < r1; j += 4) {
      bool v = (j + g) < r1;
      int s = esrc[v ? j + g : r0];
      unsigned u = *(const unsigned*)(kvb + s);
      f32x2 kd = fp8dec<false>(u);
      float d = q0 * kd.x + q1 * kd.y;
#pragma unroll
      for (int msk = 1; msk <= 8; msk <<= 1) d += __shfl_xor(d, msk);
      float p = v ? __expf(d) : 0.f;
      l += p;
      f32x2 vd = fp8dec<true>(u);
      a0 += p * vd.x;
      a1 += p * vd.y;
    }
#pragma unroll
    for (int msk = 16; msk <= 32; msk <<= 1) {
      l  += __shfl_xor(l, msk);
      a0 += __shfl_xor(a0, msk);
      a1 += __shfl_xor(a1, msk);
    }
    float inv = (l > 0.f) ? 1.f / l : 0.f;
    unsigned hu = *(const unsigned*)(C2b + (size_t)node * 256 + 192 + gl * 4);
    float o0 = fmaxf(bflo(hu) + a0 * inv, 0.f);
    float o1 = fmaxf(bfhi(hu) + a1 * inv, 0.f);
    t = o0 * Wo[2 * gl] + o1 * Wo[2 * gl + 1];
#pragma unroll
    for (int msk = 1; msk <= 8; msk <<= 1) t += __shfl_xor(t, msk);
  }
  if (lane == 0) ps[wave] = t;
  __syncthreads();
  if (threadIdx.x == 0) pblock[blockIdx.x] = ps[0] + ps[1] + ps[2] + ps[3];
}

// ---------------- final: sum per-block partials, scale, bias ----------------
__global__ void final_out(const float* __restrict__ pblock, const float* __restrict__ bo,
                          float* __restrict__ out, int nb, float invN) {
  __shared__ float s[256];
  float acc = 0.f;
  for (int i = threadIdx.x; i < nb; i += 256) acc += pblock[i];
  s[threadIdx.x] = acc;
  __syncthreads();
  for (int off = 128; off >= 1; off >>= 1) {
    if (threadIdx.x < off) s[threadIdx.x] += s[threadIdx.x + off];
    __syncthreads();
  }
  if (threadIdx.x == 0) out[0] = s[0] * invN + bo[0];
}

extern "C" void kernel_launch(void* const* d_in, const int* in_sizes, int n_in,
                              void* d_out, int out_size, void* d_ws, size_t ws_size,
                              hipStream_t stream) {
  const float* x   = (const float*)d_in[0];
  const int*   ei  = (const int*)d_in[1];  // [2, E]: row 0 = src, row 1 = dst
  const float* Wq1 = (const float*)d_in[2];  const float* bq1 = (const float*)d_in[3];
  const float* Wk1 = (const float*)d_in[4];  const float* bk1 = (const float*)d_in[5];
  const float* Wv1 = (const float*)d_in[6];  const float* bv1 = (const float*)d_in[7];
  const float* Ws1 = (const float*)d_in[8];  const float* bs1 = (const float*)d_in[9];
  const float* Wq2 = (const float*)d_in[10]; const float* bq2 = (const float*)d_in[11];
  const float* Wk2 = (const float*)d_in[12]; const float* bk2 = (const float*)d_in[13];
  const float* Wv2 = (const float*)d_in[14]; const float* bv2 = (const float*)d_in[15];
  const float* Ws2 = (const float*)d_in[16]; const float* bs2 = (const float*)d_in[17];
  const float* Wo  = (const float*)d_in[18]; const float* bo  = (const float*)d_in[19];

  char* ws = (char*)d_ws;
  const int N = N_NODES, E = N_EDGES;
  const int GB = (N + 63) / 64;
  const int EB = (E + 4095) / 4096;
  const int AB = (N * 64) / 256;   // 12500 attn blocks

  // buffers
  unsigned short* Q1b = (unsigned short*)(ws + 0);          // N*128 bf16 (pre-scaled)
  unsigned short* SK1 = (unsigned short*)(ws + 12800000);   // N*128 bf16
  unsigned char*  KV1 = (unsigned char*)(ws + 25600000);    // N*256 fp8 interleaved
  unsigned short* H1b = (unsigned short*)(ws + 51200000);   // N*128 bf16
  unsigned char*  C2  = (unsigned char*)(ws + 64000000);    // N*256 bytes [Q|KV8|pad|H]
  // CSR + weights + misc
  int* rowptr = (int*)(ws + 89600000);                      // N+1
  int* esrc   = (int*)(ws + 89900032);                      // E (byte offsets, src<<8)
  int* bhist  = (int*)(ws + 93100032);                      // NBK
  int* boff   = (int*)(ws + 93101056);                      // NBK+1
  int* bcur   = (int*)(ws + 93102080);                      // NBK
  unsigned short* Wt1   = (unsigned short*)(ws + 93103104);   // 512x128 bf16
  unsigned short* Wt2   = (unsigned short*)(ws + 93234176);   // 128x128 bf16
  float*          bcat1 = (float*)(ws + 93266944);
  float*          bcat2 = (float*)(ws + 93268992);
  float*          pblock = (float*)(ws + 93269504);         // 12500 floats
  int*            ebuck = (int*)(ws + 93319552);            // E * 4B packed

  float* out = (float*)d_out;

  dim3 blk(256);

  hipMemsetAsync(bhist, 0, NBK * sizeof(int), stream);

  // ---- fused prep: weights + bucket histogram ----
  prep_fused<<<dim3(W1_B + W2_B + EB), blk, 0, stream>>>(
      Wq1, Wk1, Wv1, Ws1, bq1, bk1, bv1, bs1,
      Wq2, Wk2, Wv2, Ws2, bq2, bk2, bv2, bs2,
      Wt1, bcat1, Wt2, bcat2, ei, bhist, E);

  // ---- bucket scan ----
  bucket_scan<<<dim3(1), blk, 0, stream>>>(bhist, boff, bcur);

  // ---- FUSED: edge scatter + conv1 GEMM (independent; run concurrently) ----
  scatter_gemm1<<<dim3(EB + GB), blk, 0, stream>>>(
      ei, bcur, ebuck, E, EB, x, Wt1, bcat1, Q1b, SK1, KV1, N);

  // ---- per-bucket CSR finalize ----
  bucket_csr<<<dim3(NBK), blk, 0, stream>>>(ebuck, boff, rowptr, esrc, N);

  // ---- conv1 fused attention + skip + relu -> bf16 ----
  node_attn1<<<dim3(AB), blk, 0, stream>>>(rowptr, esrc, Q1b, KV1, SK1, H1b, N);

  // ---- conv2 GEMM (fused Q|KV8|H rows) ----
  gemm2<<<dim3(GB), blk, 0, stream>>>(H1b, Wt2, bcat2, C2, N);

  // ---- conv2 attention + fused relu/mean/Wo-dot -> per-block partials ----
  node_attn2<<<dim3(AB), blk, 0, stream>>>(rowptr, esrc, C2, Wo, pblock, N);

  // ---- final reduce ----
  final_out<<<dim3(1), blk, 0, stream>>>(pblock, bo, out, AB, 1.0f / (float)N);
}